// Round 4
// baseline (135.906 us; speedup 1.0000x reference)
//
#include <hip/hip_runtime.h>
#include <math.h>

// Problem constants (baked from reference setup_inputs):
// B=2, N=1024, Din=64, D=64, K=24
#define BB 2
#define NN 1024
#define DD 64
#define KK 24
#define NPTS (BB * NN)  // 2048

#if __has_builtin(__builtin_amdgcn_exp2f)
#define EXP2(x) __builtin_amdgcn_exp2f(x)
#else
#define EXP2(x) exp2f(x)
#endif

typedef float v2f __attribute__((ext_vector_type(2)));

// Force VOP3P packed f32 math (LLVM does not form these from ext_vector ops).
static __device__ __forceinline__ v2f pk_fma(v2f a, v2f b, v2f c) {
    v2f d;
    asm("v_pk_fma_f32 %0, %1, %2, %3" : "=v"(d) : "v"(a), "v"(b), "v"(c));
    return d;
}
static __device__ __forceinline__ v2f pk_add(v2f a, v2f b) {
    v2f d;
    asm("v_pk_add_f32 %0, %1, %2" : "=v"(d) : "v"(a), "v"(b));
    return d;
}

// ---------------------------------------------------------------------------
// Workspace layout (bytes):
//   feat : [2048][64] float   @ 0        (512 KiB)
//   idx  : [2048][24] int     @ 524288   (192 KiB)
//   rwP  : [4096] float4      @ 720896   (64 KiB)  {rw0,rw1,rw2,rb}*log2(e)
// ---------------------------------------------------------------------------

// Fused prep + MLP + KNN, role-split by blockIdx:
//   blocks [0,512)    : MLP, 4 points per block
//   blocks [512,528)  : rw/rb prescale+interleave
//   blocks [528,1040) : KNN, 4 points per block (one wave per point)
__global__ __launch_bounds__(256) void prep_mlp_knn_kernel(
    const float* __restrict__ feature, const float* __restrict__ xyz,
    const float* __restrict__ pw1, const float* __restrict__ pb1,
    const float* __restrict__ pw2, const float* __restrict__ pb2,
    const float* __restrict__ rw, const float* __restrict__ rb,
    float* __restrict__ feat, int* __restrict__ idx_out,
    float4* __restrict__ rwP) {
    int bid = blockIdx.x;
    int tid = threadIdx.x;

    if (bid < 512) {
        // ---- MLP: feat = relu(relu(feature@pw1+pb1)@pw2+pb2), 4 rows/block
        int r = tid >> 6;
        int d = tid & 63;
        int row = bid * 4 + r;
        __shared__ float s_in[4][64];
        __shared__ float s_h[4][64];
        s_in[r][d] = feature[row * 64 + d];
        __syncthreads();
        float h = pb1[d];
#pragma unroll
        for (int i = 0; i < 64; i++) h = __builtin_fmaf(s_in[r][i], pw1[i * 64 + d], h);
        h = fmaxf(h, 0.f);
        s_h[r][d] = h;
        __syncthreads();
        float f = pb2[d];
#pragma unroll
        for (int i = 0; i < 64; i++) f = __builtin_fmaf(s_h[r][i], pw2[i * 64 + d], f);
        f = fmaxf(f, 0.f);
        feat[row * 64 + d] = f;
    } else if (bid < 528) {
        // ---- prescale rw/rb by log2(e), interleave to float4 per column
        const float LOG2E = 1.4426950408889634f;
        int t = (bid - 512) * 256 + tid;  // 0..4095
        float4 v;
        v.x = rw[t] * LOG2E;
        v.y = rw[4096 + t] * LOG2E;
        v.z = rw[8192 + t] * LOG2E;
        v.w = rb[t] * LOG2E;
        rwP[t] = v;
    } else {
        // ---- KNN: one wave per point, iterative argmin (24 rounds)
        int w = tid >> 6;
        int lane = tid & 63;
        int pt = (bid - 528) * 4 + w;
        int b = pt >> 10;
        int n = pt & 1023;
        const float* xb = xyz + (size_t)b * NN * 3;
        float xn = xb[n * 3 + 0], yn = xb[n * 3 + 1], zn = xb[n * 3 + 2];
        float sqn = xn * xn + yn * yn + zn * zn;
        float dist[16];
#pragma unroll
        for (int c = 0; c < 16; c++) {
            int m = c * 64 + lane;
            float xm = xb[m * 3 + 0], ym = xb[m * 3 + 1], zm = xb[m * 3 + 2];
            float sqm = xm * xm + ym * ym + zm * zm;
            float dot = xn * xm + yn * ym + zn * zm;
            dist[c] = sqn + sqm - 2.0f * dot;
        }
        for (int r = 0; r < KK; r++) {
            float best = 3.4e38f;
            int bi = 1 << 30;
#pragma unroll
            for (int c = 0; c < 16; c++) {
                if (dist[c] < best) {  // strict < keeps lowest index on ties
                    best = dist[c];
                    bi = c * 64 + lane;
                }
            }
#pragma unroll
            for (int off = 32; off >= 1; off >>= 1) {
                float ob = __shfl_down(best, off);
                int oi = __shfl_down(bi, off);
                if (ob < best || (ob == best && oi < bi)) {
                    best = ob;
                    bi = oi;
                }
            }
            bi = __shfl(bi, 0);
            if ((bi & 63) == lane) dist[bi >> 6] = 3.4e38f;
            if (lane == 0) idx_out[pt * KK + r] = bi;
        }
    }
}

// Fused weight-gen + softmax (over K*D, per column d) + aggregate + final
// linear. TWO points per 512-thread block (sub = tid>>8); within a sub-group
// of 256: lane = d, wave w owns j in [w*16, w*16+16).
// 512-thread blocks: probe whether small-block residency was capping
// occupancy at ~2.5 blocks/CU (R1-R3 all showed OccupancyPercent ~32%).
#define GVS 28  // s_gvt row stride (112B: 16B-aligned float4 reads, 8-way write conflict only)
__global__ __launch_bounds__(512) void agg_kernel(const float* __restrict__ xyz,
                                                  const float* __restrict__ feat,
                                                  const int* __restrict__ idx,
                                                  const float4* __restrict__ rwP,
                                                  const float* __restrict__ sw,
                                                  const float* __restrict__ sb,
                                                  float* __restrict__ out) {
    int tid = threadIdx.x;
    int sub = tid >> 8;    // which of the 2 points this block handles
    int stid = tid & 255;  // thread id within the sub-group
    int pt = blockIdx.x * 2 + sub;
    int b = pt >> 10;
    int n = pt & 1023;
    int w = stid >> 6;
    int d = stid & 63;

    __shared__ float s_rel[2][KK][3];
    __shared__ __align__(16) float s_gvt[2][64][GVS];  // [sub][j][k]
    __shared__ float s_red[2][8][64];
    __shared__ float s_pre[2][64];

    const float* xb = xyz + (size_t)b * NN * 3;
    if (stid < KK * 3) {
        int k = stid / 3, c = stid % 3;
        int nb = idx[pt * KK + k];
        s_rel[sub][k][c] = xb[nb * 3 + c] - xb[n * 3 + c];
    }
    for (int t = stid; t < KK * 64; t += 256) {
        int k = t >> 6, j = t & 63;
        int nb = idx[pt * KK + k];
        s_gvt[sub][j][k] = feat[((size_t)b * NN + nb) * 64 + j];
    }
    __syncthreads();

    // rel in registers as float2 pairs (wave-uniform values; compiler may
    // demote some back to broadcast LDS reads — cheap)
    v2f rx[12], ry[12], rz[12];
#pragma unroll
    for (int k = 0; k < 12; k++) {
        rx[k] = (v2f){s_rel[sub][2 * k][0], s_rel[sub][2 * k + 1][0]};
        ry[k] = (v2f){s_rel[sub][2 * k][1], s_rel[sub][2 * k + 1][1]};
        rz[k] = (v2f){s_rel[sub][2 * k][2], s_rel[sub][2 * k + 1][2]};
    }

    v2f l0 = {0.f, 0.f}, l1 = {0.f, 0.f}, a0 = {0.f, 0.f}, a1 = {0.f, 0.f};
    int col0 = (w * 16) * 64 + d;
    float4 rv = rwP[col0];
    for (int jj = 0; jj < 16; jj++) {
        int j = w * 16 + jj;
        // prefetch next jj's weight column while computing this one
        float4 rvn = rv;
        if (jj < 15) rvn = rwP[col0 + (jj + 1) * 64];
        v2f R0 = {rv.x, rv.x}, R1 = {rv.y, rv.y}, R2 = {rv.z, rv.z}, RB = {rv.w, rv.w};
        const float4* g4 = (const float4*)(&s_gvt[sub][j][0]);
#pragma unroll
        for (int q = 0; q < 6; q++) {
            float4 g = g4[q];
            v2f ga = {g.x, g.y};
            v2f gb = {g.z, g.w};
            v2f t0 = pk_fma(rx[2 * q], R0, pk_fma(ry[2 * q], R1, pk_fma(rz[2 * q], R2, RB)));
            v2f t1 = pk_fma(rx[2 * q + 1], R0, pk_fma(ry[2 * q + 1], R1, pk_fma(rz[2 * q + 1], R2, RB)));
            v2f e0 = {EXP2(t0.x), EXP2(t0.y)};
            v2f e1 = {EXP2(t1.x), EXP2(t1.y)};
            l0 = pk_add(l0, e0);
            l1 = pk_add(l1, e1);
            a0 = pk_fma(ga, e0, a0);
            a1 = pk_fma(gb, e1, a1);
        }
        rv = rvn;
    }
    s_red[sub][w][d] = l0.x + l0.y + l1.x + l1.y;
    s_red[sub][4 + w][d] = a0.x + a0.y + a1.x + a1.y;
    __syncthreads();
    if (stid < 64) {
        float L = s_red[sub][0][d] + s_red[sub][1][d] + s_red[sub][2][d] + s_red[sub][3][d];
        float A = s_red[sub][4][d] + s_red[sub][5][d] + s_red[sub][6][d] + s_red[sub][7][d];
        s_pre[sub][d] = A / L;
    }
    __syncthreads();
    // out[pt][d] = sum_dd s_pre[dd] * sw[dd][d] + sb[d]
    float part = 0.f;
#pragma unroll
    for (int dd = 0; dd < 16; dd++) {
        int drow = w * 16 + dd;
        part = __builtin_fmaf(s_pre[sub][drow], sw[drow * 64 + d], part);
    }
    s_red[sub][w][d] = part;
    __syncthreads();
    if (stid < 64) {
        float o = s_red[sub][0][d] + s_red[sub][1][d] + s_red[sub][2][d] + s_red[sub][3][d] + sb[d];
        out[(size_t)pt * 64 + d] = o;
    }
    if (pt == 0 && stid == 0) out[(size_t)NPTS * 64] = 1024.0f;  // second output: N
}

extern "C" void kernel_launch(void* const* d_in, const int* in_sizes, int n_in,
                              void* d_out, int out_size, void* d_ws, size_t ws_size,
                              hipStream_t stream) {
    const float* feature = (const float*)d_in[0];
    const float* xyz = (const float*)d_in[1];
    const float* pw1 = (const float*)d_in[2];
    const float* pb1 = (const float*)d_in[3];
    const float* pw2 = (const float*)d_in[4];
    const float* pb2 = (const float*)d_in[5];
    const float* rw = (const float*)d_in[6];
    const float* rb = (const float*)d_in[7];
    const float* sw = (const float*)d_in[8];
    const float* sb = (const float*)d_in[9];
    float* out = (float*)d_out;

    char* ws = (char*)d_ws;
    float* feat = (float*)(ws);             // 512 KiB
    int* idx = (int*)(ws + 524288);         // 192 KiB
    float4* rwP = (float4*)(ws + 720896);   // 64 KiB

    prep_mlp_knn_kernel<<<1040, 256, 0, stream>>>(feature, xyz, pw1, pb1, pw2, pb2,
                                                  rw, rb, feat, idx, rwP);
    agg_kernel<<<NPTS / 2, 512, 0, stream>>>(xyz, feat, idx, rwP, sw, sb, out);
}

// Round 5
// 131.727 us; speedup vs baseline: 1.0317x; 1.0317x over previous
//
#include <hip/hip_runtime.h>
#include <math.h>

// Problem constants (baked from reference setup_inputs):
// B=2, N=1024, Din=64, D=64, K=24
#define BB 2
#define NN 1024
#define DD 64
#define KK 24
#define NPTS (BB * NN)  // 2048

#if __has_builtin(__builtin_amdgcn_exp2f)
#define EXP2(x) __builtin_amdgcn_exp2f(x)
#else
#define EXP2(x) exp2f(x)
#endif

typedef float v2f __attribute__((ext_vector_type(2)));

// Force VOP3P packed f32 math (LLVM does not form these from ext_vector ops).
static __device__ __forceinline__ v2f pk_fma(v2f a, v2f b, v2f c) {
    v2f d;
    asm("v_pk_fma_f32 %0, %1, %2, %3" : "=v"(d) : "v"(a), "v"(b), "v"(c));
    return d;
}
static __device__ __forceinline__ v2f pk_add(v2f a, v2f b) {
    v2f d;
    asm("v_pk_add_f32 %0, %1, %2" : "=v"(d) : "v"(a), "v"(b));
    return d;
}

// ---------------------------------------------------------------------------
// Workspace layout (bytes):
//   feat : [2048][64] float   @ 0        (512 KiB)
//   idx  : [2048][24] int     @ 524288   (192 KiB)
//   rwP  : [4096] float4      @ 720896   (64 KiB)  {rw0,rw1,rw2,rb}*log2(e)
// ---------------------------------------------------------------------------

// Fused prep + MLP + KNN, role-split by blockIdx:
//   blocks [0,512)    : MLP, 4 points per block
//   blocks [512,528)  : rw/rb prescale+interleave
//   blocks [528,1040) : KNN, 4 points per block (one wave per point)
__global__ __launch_bounds__(256) void prep_mlp_knn_kernel(
    const float* __restrict__ feature, const float* __restrict__ xyz,
    const float* __restrict__ pw1, const float* __restrict__ pb1,
    const float* __restrict__ pw2, const float* __restrict__ pb2,
    const float* __restrict__ rw, const float* __restrict__ rb,
    float* __restrict__ feat, int* __restrict__ idx_out,
    float4* __restrict__ rwP) {
    int bid = blockIdx.x;
    int tid = threadIdx.x;

    if (bid < 512) {
        // ---- MLP: feat = relu(relu(feature@pw1+pb1)@pw2+pb2), 4 rows/block
        int r = tid >> 6;
        int d = tid & 63;
        int row = bid * 4 + r;
        __shared__ float s_in[4][64];
        __shared__ float s_h[4][64];
        s_in[r][d] = feature[row * 64 + d];
        __syncthreads();
        float h = pb1[d];
#pragma unroll
        for (int i = 0; i < 64; i++) h = __builtin_fmaf(s_in[r][i], pw1[i * 64 + d], h);
        h = fmaxf(h, 0.f);
        s_h[r][d] = h;
        __syncthreads();
        float f = pb2[d];
#pragma unroll
        for (int i = 0; i < 64; i++) f = __builtin_fmaf(s_h[r][i], pw2[i * 64 + d], f);
        f = fmaxf(f, 0.f);
        feat[row * 64 + d] = f;
    } else if (bid < 528) {
        // ---- prescale rw/rb by log2(e), interleave to float4 per column
        const float LOG2E = 1.4426950408889634f;
        int t = (bid - 512) * 256 + tid;  // 0..4095
        float4 v;
        v.x = rw[t] * LOG2E;
        v.y = rw[4096 + t] * LOG2E;
        v.z = rw[8192 + t] * LOG2E;
        v.w = rb[t] * LOG2E;
        rwP[t] = v;
    } else {
        // ---- KNN: one wave per point, iterative argmin (24 rounds)
        int w = tid >> 6;
        int lane = tid & 63;
        int pt = (bid - 528) * 4 + w;
        int b = pt >> 10;
        int n = pt & 1023;
        const float* xb = xyz + (size_t)b * NN * 3;
        float xn = xb[n * 3 + 0], yn = xb[n * 3 + 1], zn = xb[n * 3 + 2];
        float sqn = xn * xn + yn * yn + zn * zn;
        float dist[16];
#pragma unroll
        for (int c = 0; c < 16; c++) {
            int m = c * 64 + lane;
            float xm = xb[m * 3 + 0], ym = xb[m * 3 + 1], zm = xb[m * 3 + 2];
            float sqm = xm * xm + ym * ym + zm * zm;
            float dot = xn * xm + yn * ym + zn * zm;
            dist[c] = sqn + sqm - 2.0f * dot;
        }
        for (int r = 0; r < KK; r++) {
            float best = 3.4e38f;
            int bi = 1 << 30;
#pragma unroll
            for (int c = 0; c < 16; c++) {
                if (dist[c] < best) {  // strict < keeps lowest index on ties
                    best = dist[c];
                    bi = c * 64 + lane;
                }
            }
#pragma unroll
            for (int off = 32; off >= 1; off >>= 1) {
                float ob = __shfl_down(best, off);
                int oi = __shfl_down(bi, off);
                if (ob < best || (ob == best && oi < bi)) {
                    best = ob;
                    bi = oi;
                }
            }
            bi = __shfl(bi, 0);
            if ((bi & 63) == lane) dist[bi >> 6] = 3.4e38f;
            if (lane == 0) idx_out[pt * KK + r] = bi;
        }
    }
}

// Fused weight-gen + softmax (over K*D, per column d) + aggregate + final
// linear. One block (4 waves) per point; lane = d; wave w owns j in
// [w*16, w*16+16). Hot loop: v_pk_fma_f32 + v_exp_f32.
// __launch_bounds__(256, 1): VGPR cap 256 so the 72-VGPR rel working set
// (rx/ry/rz, loop-invariant) stays IN REGISTERS. At the default cap (64
// VGPRs / 8 waves) the compiler demoted it to per-use LDS/scratch re-reads
// inside the hot loop — R1-R4 all ran ~3x slower than the clean-register
// issue model predicts.
#define GVS 28  // s_gvt row stride (112B: 16B-aligned float4 reads, 8-way write conflict only)
__global__ __launch_bounds__(256, 1) void agg_kernel(const float* __restrict__ xyz,
                                                     const float* __restrict__ feat,
                                                     const int* __restrict__ idx,
                                                     const float4* __restrict__ rwP,
                                                     const float* __restrict__ sw,
                                                     const float* __restrict__ sb,
                                                     float* __restrict__ out) {
    int pt = blockIdx.x;
    int b = pt >> 10;
    int n = pt & 1023;
    int tid = threadIdx.x;
    int w = tid >> 6;
    int d = tid & 63;

    __shared__ __align__(8) float s_relT[3][28];    // [c][k], padded
    __shared__ __align__(16) float s_gvt[64][GVS];  // [j][k]
    __shared__ float s_red[8][64];
    __shared__ float s_pre[64];

    const float* xb = xyz + (size_t)b * NN * 3;
    if (tid < KK * 3) {
        int k = tid % KK, c = tid / KK;
        int nb = idx[pt * KK + k];
        s_relT[c][k] = xb[nb * 3 + c] - xb[n * 3 + c];
    }
    for (int t = tid; t < KK * 64; t += 256) {
        int k = t >> 6, j = t & 63;
        int nb = idx[pt * KK + k];
        s_gvt[j][k] = feat[((size_t)b * NN + nb) * 64 + j];
    }
    __syncthreads();

    // rel pairs in registers (contiguous v2f loads from transposed layout)
    v2f rx[12], ry[12], rz[12];
#pragma unroll
    for (int k = 0; k < 12; k++) {
        rx[k] = *(const v2f*)&s_relT[0][2 * k];
        ry[k] = *(const v2f*)&s_relT[1][2 * k];
        rz[k] = *(const v2f*)&s_relT[2][2 * k];
    }

    v2f l0 = {0.f, 0.f}, l1 = {0.f, 0.f}, a0 = {0.f, 0.f}, a1 = {0.f, 0.f};
    int col0 = (w * 16) * 64 + d;
    float4 rv = rwP[col0];
    for (int jj = 0; jj < 16; jj++) {
        int j = w * 16 + jj;
        // prefetch next jj's weight column while computing this one
        float4 rvn = rv;
        if (jj < 15) rvn = rwP[col0 + (jj + 1) * 64];
        v2f R0 = {rv.x, rv.x}, R1 = {rv.y, rv.y}, R2 = {rv.z, rv.z}, RB = {rv.w, rv.w};
        const float4* g4 = (const float4*)(&s_gvt[j][0]);
#pragma unroll
        for (int q = 0; q < 6; q++) {
            float4 g = g4[q];
            v2f ga = {g.x, g.y};
            v2f gb = {g.z, g.w};
            v2f t0 = pk_fma(rx[2 * q], R0, pk_fma(ry[2 * q], R1, pk_fma(rz[2 * q], R2, RB)));
            v2f t1 = pk_fma(rx[2 * q + 1], R0, pk_fma(ry[2 * q + 1], R1, pk_fma(rz[2 * q + 1], R2, RB)));
            v2f e0 = {EXP2(t0.x), EXP2(t0.y)};
            v2f e1 = {EXP2(t1.x), EXP2(t1.y)};
            l0 = pk_add(l0, e0);
            l1 = pk_add(l1, e1);
            a0 = pk_fma(ga, e0, a0);
            a1 = pk_fma(gb, e1, a1);
        }
        rv = rvn;
    }
    s_red[w][d] = l0.x + l0.y + l1.x + l1.y;
    s_red[4 + w][d] = a0.x + a0.y + a1.x + a1.y;
    __syncthreads();
    if (tid < 64) {
        float L = s_red[0][d] + s_red[1][d] + s_red[2][d] + s_red[3][d];
        float A = s_red[4][d] + s_red[5][d] + s_red[6][d] + s_red[7][d];
        s_pre[d] = A / L;
    }
    __syncthreads();
    // out[pt][d] = sum_dd s_pre[dd] * sw[dd][d] + sb[d]
    float part = 0.f;
#pragma unroll
    for (int dd = 0; dd < 16; dd++) {
        int drow = w * 16 + dd;
        part = __builtin_fmaf(s_pre[drow], sw[drow * 64 + d], part);
    }
    s_red[w][d] = part;
    __syncthreads();
    if (tid < 64) {
        float o = s_red[0][d] + s_red[1][d] + s_red[2][d] + s_red[3][d] + sb[d];
        out[(size_t)pt * 64 + d] = o;
    }
    if (pt == 0 && tid == 0) out[(size_t)NPTS * 64] = 1024.0f;  // second output: N
}

extern "C" void kernel_launch(void* const* d_in, const int* in_sizes, int n_in,
                              void* d_out, int out_size, void* d_ws, size_t ws_size,
                              hipStream_t stream) {
    const float* feature = (const float*)d_in[0];
    const float* xyz = (const float*)d_in[1];
    const float* pw1 = (const float*)d_in[2];
    const float* pb1 = (const float*)d_in[3];
    const float* pw2 = (const float*)d_in[4];
    const float* pb2 = (const float*)d_in[5];
    const float* rw = (const float*)d_in[6];
    const float* rb = (const float*)d_in[7];
    const float* sw = (const float*)d_in[8];
    const float* sb = (const float*)d_in[9];
    float* out = (float*)d_out;

    char* ws = (char*)d_ws;
    float* feat = (float*)(ws);             // 512 KiB
    int* idx = (int*)(ws + 524288);         // 192 KiB
    float4* rwP = (float4*)(ws + 720896);   // 64 KiB

    prep_mlp_knn_kernel<<<1040, 256, 0, stream>>>(feature, xyz, pw1, pb1, pw2, pb2,
                                                  rw, rb, feat, idx, rwP);
    agg_kernel<<<NPTS, 256, 0, stream>>>(xyz, feat, idx, rwP, sw, sb, out);
}